// Round 3
// baseline (888.789 us; speedup 1.0000x reference)
//
#include <hip/hip_runtime.h>
#include <hip/hip_bf16.h>
#include <hip/hip_fp16.h>
#include <math.h>

// GraphAttentionLayer fused kernel v3, MI355X (gfx950).
//
// Math identity (see v1): row softmax of a row-constant logit collapses to
// 1/cnt over unmasked entries, so
//   out[n,m] = adj[n,m]>0 ? elu(h[n,m]/cnt[n]) : 0,  h = X @ W  (`a` unused)
//
// v3 changes vs v2 (378us, latency/barrier-bound, 1 block/CU):
//  - SINGLE-TERM f16 GEMM (f16 X * f16 W, fp32 accum). Error ~2e-5 on out,
//    far under the 2.44e-4 ref-side absmax floor (v1/v2 bit-identical absmax
//    across different MFMA shapes proves the floor isn't our GEMM).
//    -> MFMA work 3x down (21us floor), LDS/W traffic 2x down.
//  - LDS 66KB/block -> 2 blocks/CU (16 waves/CU): barrier drains in one
//    block are filled by the other. Kernel is now HBM-bound (~130us floor).
//  - adj read spread across the 16 K-chunks (1 int4/thread/chunk, regs),
//    overlapping with MFMA instead of serializing at block start.

#define NROWS  200000
#define K_DIM  512
#define C_DIM  256
#define BM     128
#define BK     32
#define NCHUNK 16
#define LSTR   40                          // shorts per LDS row: 32 data + 8 pad = 80 B
#define CHUNK_BYTES (C_DIM * LSTR * 2)     // 20480 B per packed-W k-chunk
#define WPACK_BYTES (NCHUNK * CHUNK_BYTES) // 327680 B

typedef _Float16 f16x8 __attribute__((ext_vector_type(8)));
typedef float    f32x4  __attribute__((ext_vector_type(4)));
typedef float    f32x16 __attribute__((ext_vector_type(16)));

// Pre-cast + transpose W into LDS-image layout [chunk][col][k_local(+pad)].
__global__ void prep_w(const float* __restrict__ W, _Float16* __restrict__ wh) {
  int idx = blockIdx.x * 256 + threadIdx.x;   // = k*256 + c
  int k = idx >> 8, c = idx & 255;
  wh[((k >> 5) * C_DIM + c) * LSTR + (k & 31)] = (_Float16)W[idx];
}

__device__ __forceinline__ void gload16(const void* g, void* l) {
  __builtin_amdgcn_global_load_lds(
      (const __attribute__((address_space(1))) unsigned*)g,
      (__attribute__((address_space(3))) unsigned*)l, 16, 0, 0);
}

__global__ void __launch_bounds__(512, 4)
gat_kernel(const float* __restrict__ X, const int* __restrict__ adj,
           const _Float16* __restrict__ wh, float* __restrict__ out) {
  __shared__ _Float16 Ah[2][BM * LSTR];     // 2 x 10240 B
  __shared__ _Float16 Bh[2][C_DIM * LSTR];  // 2 x 20480 B
  __shared__ float    invl[BM];
  __shared__ unsigned maskl[BM][8];         // total LDS = 66048 B -> 2 blocks/CU

  const int tid  = threadIdx.x;
  const int lane = tid & 63;
  const int wv   = tid >> 6;    // 0..7 -> 4x2 wave grid
  const int wm   = wv >> 1;     // wave row group (32 rows)
  const int wn   = wv & 1;      // wave col group (128 cols)
  const int l31  = lane & 31;
  const int hi   = lane >> 5;
  const long r0  = (long)blockIdx.x * BM;

  // staging geometry: 4 threads per row
  const int sr = tid >> 2;            // 0..127
  const int sq = tid & 3;
  long srow = r0 + sr; if (srow > NROWS - 1) srow = NROWS - 1;
  const float* xbase = X + srow * K_DIM + sq * 8;
  const int aoff = sr * LSTR + sq * 8;          // shorts
  const int4* adjp = (const int4*)(adj + srow * C_DIM) + sq * 16;

  f32x16 acc[4];
#pragma unroll
  for (int n = 0; n < 4; ++n) acc[n] = (f32x16)(0.0f);

  f32x4 xa, xb; int4 av;
  // ---- prologue: stage chunk 0 into buffer 0 ----
  {
    xa = *(const f32x4*)(xbase + 0);
    xb = *(const f32x4*)(xbase + 4);
    av = adjp[0];
#pragma unroll
    for (int i = 0; i < 3; ++i) {
      int bi = wv + i * 8;
      if (bi < 20)
        gload16((const char*)wh + bi * 1024 + lane * 16, (char*)Bh[0] + bi * 1024);
    }
    f16x8 hv;
#pragma unroll
    for (int e = 0; e < 4; ++e) { hv[e] = (_Float16)xa[e]; hv[e + 4] = (_Float16)xb[e]; }
    *(f16x8*)&Ah[0][aoff] = hv;
  }
  __syncthreads();

  unsigned w0 = 0, w1 = 0; int cnt = 0;
  int cur = 0;
  for (int ck = 0; ck < NCHUNK; ++ck) {
    const bool pf = (ck + 1 < NCHUNK);
    f32x4 nxa, nxb; int4 nav;
    if (pf) {
      // issue-early: next X to regs, next adj int4, next B global->LDS (other buf)
      nxa = *(const f32x4*)(xbase + (ck + 1) * BK);
      nxb = *(const f32x4*)(xbase + (ck + 1) * BK + 4);
      nav = adjp[ck + 1];
      const char* s = (const char*)wh + (ck + 1) * CHUNK_BYTES;
      char* d = (char*)Bh[cur ^ 1];
#pragma unroll
      for (int i = 0; i < 3; ++i) {
        int bi = wv + i * 8;
        if (bi < 20) gload16(s + bi * 1024 + lane * 16, d + bi * 1024);
      }
    }
    // ---- compute current buffer ----
#pragma unroll
    for (int s2 = 0; s2 < 2; ++s2) {
      const int ko = s2 * 16 + hi * 8;
      f16x8 a = *(const f16x8*)&Ah[cur][(wm * 32 + l31) * LSTR + ko];
#pragma unroll
      for (int n = 0; n < 4; ++n) {
        f16x8 b = *(const f16x8*)&Bh[cur][(wn * 128 + n * 32 + l31) * LSTR + ko];
        acc[n] = __builtin_amdgcn_mfma_f32_32x32x16_f16(a, b, acc[n], 0, 0, 0);
      }
    }
    // ---- adj nibble for this chunk (hides under MFMA) ----
    {
      unsigned b = (unsigned)((av.x > 0) | ((av.y > 0) << 1) |
                              ((av.z > 0) << 2) | ((av.w > 0) << 3));
      cnt += __popc(b);
      if (ck < 8) w0 |= b << (ck * 4); else w1 |= b << ((ck - 8) * 4);
    }
    if (pf) {
      // write-late: convert next X and store to other buffer
      f16x8 hv;
#pragma unroll
      for (int e = 0; e < 4; ++e) { hv[e] = (_Float16)nxa[e]; hv[e + 4] = (_Float16)nxb[e]; }
      *(f16x8*)&Ah[cur ^ 1][aoff] = hv;
      av = nav;
      __syncthreads();   // drains gloads (vmcnt) + ds_writes for next buf
    }
    cur ^= 1;
  }

  // ---- adjacency reduce + publish ----
  cnt += __shfl_xor(cnt, 1);   // 4 threads of one row are consecutive lanes
  cnt += __shfl_xor(cnt, 2);
  if (cnt == 0) { w0 = 0xffffffffu; w1 = 0xffffffffu; }  // softmax = 1/256
  maskl[sr][sq * 2]     = w0;
  maskl[sr][sq * 2 + 1] = w1;
  if (sq == 0) invl[sr] = (cnt > 0) ? (1.0f / (float)cnt) : (1.0f / 256.0f);
  __syncthreads();

  // ---- fused epilogue: out = mask ? elu(h * inv) : 0 ----
  // C/D 32x32 layout: col = lane&31, row = (reg&3) + 8*(reg>>2) + 4*(lane>>5)
#pragma unroll
  for (int n = 0; n < 4; ++n) {
    const int col = wn * 128 + n * 32 + l31;
    const int mwi = col >> 5;
#pragma unroll
    for (int g = 0; g < 4; ++g) {
#pragma unroll
      for (int rb = 0; rb < 4; ++rb) {
        const int reg = g * 4 + rb;
        const int row = wm * 32 + rb + g * 8 + hi * 4;
        const long rr = r0 + row;
        if (rr < NROWS) {
          float inv = invl[row];
          unsigned mw = maskl[row][mwi];
          float h = acc[n][reg];
          float o = 0.0f;
          if ((mw >> (col & 31)) & 1u) {
            float hp = h * inv;
            o = hp > 0.0f ? hp : expm1f(hp);
          }
          out[rr * C_DIM + col] = o;
        }
      }
    }
  }
}

extern "C" void kernel_launch(void* const* d_in, const int* in_sizes, int n_in,
                              void* d_out, int out_size, void* d_ws, size_t ws_size,
                              hipStream_t stream) {
  const float* X   = (const float*)d_in[0];   // [200000,512] fp32
  const int*   adj = (const int*)d_in[1];     // [200000,256] int32
  const float* W   = (const float*)d_in[2];   // [512,256] fp32
  // d_in[3] (`a`) is mathematically unused (row-constant softmax cancels it).
  _Float16* wh = (_Float16*)d_ws;             // 328KB of ws

  prep_w<<<512, 256, 0, stream>>>(W, wh);
  const int nblk = (NROWS + BM - 1) / BM;     // 1563, last block partial
  gat_kernel<<<nblk, 512, 0, stream>>>(X, adj, wh, (float*)d_out);
}